// Round 4
// baseline (268.632 us; speedup 1.0000x reference)
//
#include <hip/hip_runtime.h>
#include <math.h>

#define NEG_INF -1e9f

// ---------------------------------------------------------------------------
// K1: energy[n,t] = dot(key[n,t,:], query[n,:]) for t < len, else NEG_INF.
// Wave = 4 groups x 16 lanes; each group owns one row; 4 row-quads per wave
// (16 rows/wave). One __shfl_xor stage reduces 4 rows at once.
// Fully-masked 16-row spans read nothing.
// ---------------------------------------------------------------------------
__global__ __launch_bounds__(256) void energy_kernel(
    const float* __restrict__ query,   // (N, D=256)
    const float* __restrict__ key,     // (N, T, D)
    const int*   __restrict__ lens,    // (N,)
    float*       __restrict__ energy,  // (N, T)
    int T)
{
    const int D = 256;
    const int ROWS = 16;
    const int wave = (int)((blockIdx.x * blockDim.x + threadIdx.x) >> 6);
    const int lane = threadIdx.x & 63;
    const int g    = lane >> 4;                // 0..3
    const int sub  = lane & 15;                // 0..15
    const int wavesPerN = T / ROWS;            // 128
    const int n    = wave / wavesPerN;
    const int base = (wave % wavesPerN) * ROWS;

    const int len = lens[n];
    float* erow = energy + (long long)n * T;

    if (base >= len) {
        if (sub == 0) {
            #pragma unroll
            for (int rq = 0; rq < 4; ++rq)
                erow[base + rq * 4 + g] = NEG_INF;
        }
        return;
    }

    const float* qn = query + (long long)n * D;
    const float4 q0 = *reinterpret_cast<const float4*>(qn + sub * 4);
    const float4 q1 = *reinterpret_cast<const float4*>(qn + sub * 4 + 64);
    const float4 q2 = *reinterpret_cast<const float4*>(qn + sub * 4 + 128);
    const float4 q3 = *reinterpret_cast<const float4*>(qn + sub * 4 + 192);

    #pragma unroll
    for (int rq = 0; rq < 4; ++rq) {
        const int row = base + rq * 4 + g;
        const bool act = row < len;
        float p = 0.f;
        if (act) {
            const float* kr = key + ((long long)n * T + row) * D + sub * 4;
            const float4 a = *reinterpret_cast<const float4*>(kr);
            const float4 b = *reinterpret_cast<const float4*>(kr + 64);
            const float4 c = *reinterpret_cast<const float4*>(kr + 128);
            const float4 d = *reinterpret_cast<const float4*>(kr + 192);
            p  = a.x*q0.x + a.y*q0.y + a.z*q0.z + a.w*q0.w;
            p += b.x*q1.x + b.y*q1.y + b.z*q1.z + b.w*q1.w;
            p += c.x*q2.x + c.y*q2.y + c.z*q2.z + c.w*q2.w;
            p += d.x*q3.x + d.y*q3.y + d.z*q3.z + d.w*q3.w;
        }
        p += __shfl_xor(p, 1, 64);
        p += __shfl_xor(p, 2, 64);
        p += __shfl_xor(p, 4, 64);
        p += __shfl_xor(p, 8, 64);
        if (sub == 0)
            erow[row] = act ? p : NEG_INF;
    }
}

// ---------------------------------------------------------------------------
// K2: in-place row softmax over T=2048. One block (256 threads) per n.
// Wave-shuffle reductions; only 4-element cross-wave combine in LDS.
// ---------------------------------------------------------------------------
__global__ __launch_bounds__(256) void softmax_kernel(
    float* __restrict__ att,  // (N, T)
    int T)
{
    __shared__ float smax[4];
    __shared__ float ssum[4];
    const int n    = blockIdx.x;
    const int tid  = threadIdx.x;
    const int wid  = tid >> 6;
    const int lane = tid & 63;
    float* row = att + (long long)n * T;

    float vals[8];
    float m = -INFINITY;
    #pragma unroll
    for (int i = 0; i < 8; ++i) {
        vals[i] = row[tid + (i << 8)];
        m = fmaxf(m, vals[i]);
    }
    #pragma unroll
    for (int off = 32; off >= 1; off >>= 1)
        m = fmaxf(m, __shfl_xor(m, off, 64));
    if (lane == 0) smax[wid] = m;
    __syncthreads();
    m = fmaxf(fmaxf(smax[0], smax[1]), fmaxf(smax[2], smax[3]));

    float sum = 0.f;
    #pragma unroll
    for (int i = 0; i < 8; ++i) {
        vals[i] = __expf(vals[i] - m);
        sum += vals[i];
    }
    #pragma unroll
    for (int off = 32; off >= 1; off >>= 1)
        sum += __shfl_xor(sum, off, 64);
    if (lane == 0) ssum[wid] = sum;
    __syncthreads();
    const float inv = 1.0f / (ssum[0] + ssum[1] + ssum[2] + ssum[3]);
    #pragma unroll
    for (int i = 0; i < 8; ++i)
        row[tid + (i << 8)] = vals[i] * inv;
}

// ---------------------------------------------------------------------------
// K3: context[n,v] += sum_t att[n,t] * value[n,t,v]. V == 256.
// Block = 256 threads (4 waves), 128-row chunk; wave handles 32 rows.
// Full chunks: fully-unrolled, 2 independent accumulator chains (MLP).
// Partial chunks: runtime loop. Blocks entirely past len exit early.
// ---------------------------------------------------------------------------
__global__ __launch_bounds__(256) void context_kernel(
    const float* __restrict__ att,     // (N, T)
    const float* __restrict__ value,   // (N, T, V)
    const int*   __restrict__ lens,    // (N,)
    float*       __restrict__ context, // (N, V), pre-zeroed
    int T)
{
    const int V = 256;
    const int CHUNK = 128;
    __shared__ float red[4][256];

    const int n   = blockIdx.y;
    const int t0  = blockIdx.x * CHUNK;
    const int len = lens[n];
    if (t0 >= len) return;

    const int rows = min(len - t0, CHUNK);
    const int wid  = threadIdx.x >> 6;
    const int lane = threadIdx.x & 63;
    const int v4   = lane * 4;

    const float* arow  = att + (long long)n * T + t0 + wid * 32;
    const float* vrow  = value + ((long long)n * T + t0 + wid * 32) * V + v4;

    float4 acc0 = make_float4(0.f, 0.f, 0.f, 0.f);
    float4 acc1 = make_float4(0.f, 0.f, 0.f, 0.f);

    if (rows == CHUNK) {
        // Fast path: 32 rows, unrolled, two independent chains.
        #pragma unroll
        for (int u = 0; u < 16; ++u) {
            const float a0 = arow[2 * u];
            const float a1 = arow[2 * u + 1];
            const float4 v0 = *reinterpret_cast<const float4*>(vrow + (long long)(2 * u) * V);
            const float4 v1 = *reinterpret_cast<const float4*>(vrow + (long long)(2 * u + 1) * V);
            acc0.x += a0 * v0.x; acc0.y += a0 * v0.y;
            acc0.z += a0 * v0.z; acc0.w += a0 * v0.w;
            acc1.x += a1 * v1.x; acc1.y += a1 * v1.y;
            acc1.z += a1 * v1.z; acc1.w += a1 * v1.w;
        }
    } else {
        const int s = wid * 32;
        const int e = min(s + 32, rows);
        for (int i = s; i < e; ++i) {
            const float a = att[(long long)n * T + t0 + i];
            const float4 v0 = *reinterpret_cast<const float4*>(
                value + ((long long)n * T + t0 + i) * V + v4);
            acc0.x += a * v0.x; acc0.y += a * v0.y;
            acc0.z += a * v0.z; acc0.w += a * v0.w;
        }
    }

    acc0.x += acc1.x; acc0.y += acc1.y; acc0.z += acc1.z; acc0.w += acc1.w;
    *reinterpret_cast<float4*>(&red[wid][v4]) = acc0;
    __syncthreads();

    const int v = threadIdx.x;
    const float s = red[0][v] + red[1][v] + red[2][v] + red[3][v];
    atomicAdd(context + (long long)n * V + v, s);
}

// ---------------------------------------------------------------------------
extern "C" void kernel_launch(void* const* d_in, const int* in_sizes, int n_in,
                              void* d_out, int out_size, void* d_ws, size_t ws_size,
                              hipStream_t stream) {
    const float* query = (const float*)d_in[0];
    const float* key   = (const float*)d_in[1];
    const float* value = (const float*)d_in[2];
    const int*   lens  = (const int*)d_in[3];

    const int N = in_sizes[3];                 // 64
    const int D = in_sizes[0] / N;             // 256
    const int T = in_sizes[1] / (N * D);       // 2048
    const int V = in_sizes[2] / (N * T);       // 256
    (void)D; (void)V; (void)d_ws; (void)ws_size; (void)n_in; (void)out_size;

    float* context = (float*)d_out;                    // (N, V)
    float* att     = (float*)d_out + (long long)N * V; // (N, T)

    hipMemsetAsync(context, 0, (size_t)N * V * sizeof(float), stream);

    {
        long long waves = (long long)N * T / 16;
        int blocks = (int)((waves + 3) / 4);
        energy_kernel<<<blocks, 256, 0, stream>>>(query, key, lens, att, T);
    }
    softmax_kernel<<<N, 256, 0, stream>>>(att, T);
    {
        dim3 grid(T / 128, N);
        context_kernel<<<grid, 256, 0, stream>>>(att, value, lens, context, T);
    }
}